// Round 3
// baseline (123.458 us; speedup 1.0000x reference)
//
#include <hip/hip_runtime.h>

// Sliding-window causal attention, B=2 H=8 S=4096 D=64, window=512.
// R8: single fused kernel — prep + workspace eliminated.
//   K: register-direct from fp32 global (2 float4 + 4 cvt_pk per A-frag),
//      next tile's loads issued before current tile's compute.
//   V: per-tile transpose staged into double-buffered swizzled LDS image
//      (identical layout to the verified R6/R7 consumer).
//   Softmax: swapped QK^T, m=0 fixed shift, exp2-folded scale, lane-local
//   l-sum, in-register P transpose via cvt_pk + permlane32_swap.
//   Bijective XCD swizzle: each XCD owns 2 bh panels (K/V fp32 slice ~4 MB).

#define NBATCH 2
#define NHEAD  8
#define SEQ    4096
#define DH     64
#define WIN    512
#define QT     128
#define KT     64

typedef __attribute__((ext_vector_type(4)))  float f32x4;
typedef __attribute__((ext_vector_type(16))) float f32x16;
typedef __attribute__((ext_vector_type(8)))  short bf16x8;
typedef unsigned short ushort_t;

__device__ __forceinline__ unsigned short f2bf(float f) {
  unsigned u = __builtin_bit_cast(unsigned, f);
  u += 0x7fffu + ((u >> 16) & 1u);
  return (unsigned short)(u >> 16);
}

__device__ __forceinline__ unsigned pkbf16(float a, float b) {
  unsigned d;
  asm("v_cvt_pk_bf16_f32 %0, %1, %2" : "=v"(d) : "v"(a), "v"(b));
  return d;
}

// ---------------------------------------------------------------------------
// Fused attention: one block = 128 queries of one (b,h); 4 waves x 32 queries.
// ---------------------------------------------------------------------------
__global__ __launch_bounds__(256, 2) void swa_attn_fused(
    const float* __restrict__ Qg, const float* __restrict__ Kg,
    const float* __restrict__ Vg, float* __restrict__ Og)
{
  // bijective XCD swizzle: 512 blocks, 8 XCDs, 64 blocks/XCD = 2 bh panels.
  const int flat = blockIdx.y * gridDim.x + blockIdx.x;      // 0..511
  const int swz  = (flat & 7) * 64 + (flat >> 3);
  const int qt = swz & 31, bh = swz >> 5;

  const int q0 = qt * QT;
  const size_t base = (size_t)bh * SEQ * DH;
  const int t = threadIdx.x, w = t >> 6, l = t & 63;
  const int ql = l & 31, h = l >> 5;

  // V image: row = d (128 B), key-block b at byte ((b ^ (d&7))<<4), 8 keys/blk.
  __shared__ ushort_t Vt[2][4096];   // 16 KB double buffer

  const int kt_hi = 2 * qt + 1;
  const int kt_lo = (2 * qt - 8 > 0) ? (2 * qt - 8) : 0;
  const int NT = kt_hi - kt_lo + 1;   // 2..10

  const int lo = q0 + 32 * w;   // this wave's min query row
  const int hi = lo + 31;       // max query row

  // ---- Q loads FIRST (oldest in vmcnt queue) ----
  const float* qrow = Qg + base + (size_t)(lo + ql) * DH;
  float4 qa[4], qb[4];
  #pragma unroll
  for (int tf = 0; tf < 4; ++tf) {
    qa[tf] = *(const float4*)(qrow + 16 * tf + 8 * h);
    qb[tf] = *(const float4*)(qrow + 16 * tf + 8 * h + 4);
  }

  // ---- staging state ----
  float4 kf[16];   // fp32 K staging (8 frags x 2 float4), wave-private
  bf16x8 ak[8];    // current tile's K A-frags
  float  vf[16];   // fp32 V staging: this thread = d-column l, keys 16w..16w+15

  auto loadK = [&](int kt) {
    #pragma unroll
    for (int kb = 0; kb < 2; ++kb)
      #pragma unroll
      for (int tf = 0; tf < 4; ++tf) {
        const float* p = Kg + base + (size_t)(kt * KT + 32 * kb + ql) * DH
                         + 16 * tf + 8 * h;
        kf[(kb * 4 + tf) * 2 + 0] = *(const float4*)p;
        kf[(kb * 4 + tf) * 2 + 1] = *(const float4*)(p + 4);
      }
  };
  auto convK = [&]() {
    #pragma unroll
    for (int f = 0; f < 8; ++f) {
      union { unsigned u[4]; bf16x8 v; } o;
      float4 c0 = kf[2 * f], c1 = kf[2 * f + 1];
      o.u[0] = pkbf16(c0.x, c0.y); o.u[1] = pkbf16(c0.z, c0.w);
      o.u[2] = pkbf16(c1.x, c1.y); o.u[3] = pkbf16(c1.z, c1.w);
      ak[f] = o.v;
    }
  };
  auto loadV = [&](int kt) {
    const float* p = Vg + base + (size_t)(kt * KT + 16 * w) * DH + l;
    #pragma unroll
    for (int j = 0; j < 16; ++j) vf[j] = p[j * DH];
  };
  auto writeV = [&](int buf) {
    char* vb = (char*)&Vt[buf][0] + l * 128;
    #pragma unroll
    for (int jj = 0; jj < 2; ++jj) {
      union { unsigned u[4]; uint4 q; } o;
      o.u[0] = pkbf16(vf[8 * jj + 0], vf[8 * jj + 1]);
      o.u[1] = pkbf16(vf[8 * jj + 2], vf[8 * jj + 3]);
      o.u[2] = pkbf16(vf[8 * jj + 4], vf[8 * jj + 5]);
      o.u[3] = pkbf16(vf[8 * jj + 6], vf[8 * jj + 7]);
      *(uint4*)(vb + (((2 * w + jj) ^ (l & 7)) << 4)) = o.q;
    }
  };
  auto isActive = [&](int kt) {
    const int k0 = kt * KT;
    return (k0 <= hi) && (k0 + KT - 1 >= lo - (WIN - 1));
  };

  // ---- prologue: tile 0 staging overlapped with Q conversion ----
  loadV(kt_hi);
  bool actCur = isActive(kt_hi);
  if (actCur) loadK(kt_hi);

  // Q as B-frags, prescaled by (1/8)*log2(e) so softmax is raw v_exp_f32.
  const float QS = 0.125f * 1.44269504088896f;
  bf16x8 aq[4];
  #pragma unroll
  for (int tf = 0; tf < 4; ++tf) {
    union { unsigned short us[8]; bf16x8 v; } u;
    u.us[0]=f2bf(qa[tf].x*QS); u.us[1]=f2bf(qa[tf].y*QS);
    u.us[2]=f2bf(qa[tf].z*QS); u.us[3]=f2bf(qa[tf].w*QS);
    u.us[4]=f2bf(qb[tf].x*QS); u.us[5]=f2bf(qb[tf].y*QS);
    u.us[6]=f2bf(qb[tf].z*QS); u.us[7]=f2bf(qb[tf].w*QS);
    aq[tf] = u.v;
  }

  if (actCur) convK();
  writeV(0);
  __syncthreads();

  f32x16 acc[2];
  #pragma unroll
  for (int db = 0; db < 2; ++db)
    #pragma unroll
    for (int r = 0; r < 16; ++r) acc[db][r] = 0.0f;
  float lsum = 0.0f;

  for (int i = 0; i < NT; ++i) {
    const int kt = kt_hi - i;
    const int k0 = kt * KT;

    // issue next tile's global loads before this tile's compute
    bool actNext = false;
    if (i + 1 < NT) {
      loadV(kt - 1);
      actNext = isActive(kt - 1);
      if (actNext) loadK(kt - 1);
    }

    if (actCur) {
      const char* vbuf = (const char*)&Vt[i & 1][0];

      // ---- S^T = K Q^T : lane holds P[k = 32*kb + a(r) + 4h][q = lo+ql] ----
      f32x16 p[2];
      #pragma unroll
      for (int kb = 0; kb < 2; ++kb) {
        f32x16 c;
        #pragma unroll
        for (int r = 0; r < 16; ++r) c[r] = 0.0f;
        #pragma unroll
        for (int tf = 0; tf < 4; ++tf)
          c = __builtin_amdgcn_mfma_f32_32x32x16_bf16(ak[kb * 4 + tf], aq[tf], c, 0, 0, 0);
        p[kb] = c;
      }

      // ---- exp2 (m=0 fixed shift, exact) + tree-reduced lane-local l-sum ----
      const int dbase = k0 - (lo + ql) + 4 * h;
      const bool needmask = (k0 + KT - 1 > lo) || (k0 < hi - (WIN - 1));
      float ps0 = 0.f, ps1 = 0.f, ps2 = 0.f, ps3 = 0.f;
      if (needmask) {
        #pragma unroll
        for (int kb = 0; kb < 2; ++kb)
          #pragma unroll
          for (int r = 0; r < 16; ++r) {
            const int dji = dbase + 32 * kb + ((r & 3) + 8 * (r >> 2));
            float s = ((unsigned)(dji + (WIN - 1)) <= (unsigned)(WIN - 1))
                          ? p[kb][r] : -1e30f;
            float e = __builtin_amdgcn_exp2f(s);
            p[kb][r] = e;
            if ((r & 3) == 0) ps0 += e;
            else if ((r & 3) == 1) ps1 += e;
            else if ((r & 3) == 2) ps2 += e;
            else ps3 += e;
          }
      } else {
        #pragma unroll
        for (int kb = 0; kb < 2; ++kb)
          #pragma unroll
          for (int r = 0; r < 16; ++r) {
            float e = __builtin_amdgcn_exp2f(p[kb][r]);
            p[kb][r] = e;
            if ((r & 3) == 0) ps0 += e;
            else if ((r & 3) == 1) ps1 += e;
            else if ((r & 3) == 2) ps2 += e;
            else ps3 += e;
          }
      }
      lsum += (ps0 + ps1) + (ps2 + ps3);

      // ---- in-register P transpose -> A-frags, fused with O += P V ----
      #pragma unroll
      for (int kb = 0; kb < 2; ++kb) {
        #pragma unroll
        for (int b = 0; b < 2; ++b) {
          unsigned x0 = pkbf16(p[kb][8*b+0], p[kb][8*b+1]);
          unsigned x1 = pkbf16(p[kb][8*b+2], p[kb][8*b+3]);
          unsigned y0 = pkbf16(p[kb][8*b+4], p[kb][8*b+5]);
          unsigned y1 = pkbf16(p[kb][8*b+6], p[kb][8*b+7]);
          asm("v_permlane32_swap_b32 %0, %1" : "+v"(x0), "+v"(y0));
          asm("v_permlane32_swap_b32 %0, %1" : "+v"(x1), "+v"(y1));
          union { unsigned u[4]; bf16x8 v; } fa;
          fa.u[0] = x0; fa.u[1] = x1; fa.u[2] = y0; fa.u[3] = y1;
          const int ks = 2 * kb + b;   // k-slice 16*ks .. 16*ks+15
          #pragma unroll
          for (int db = 0; db < 2; ++db) {
            const int vrow = 32 * db + ql;
            bf16x8 vb = *(const bf16x8*)(vbuf + vrow * 128 +
                                         (((2*ks + h) ^ (vrow & 7)) << 4));
            acc[db] = __builtin_amdgcn_mfma_f32_32x32x16_bf16(fa.v, vb, acc[db], 0, 0, 0);
          }
        }
      }
    }

    // convert next K, commit next V image, then fence the buffer swap
    if (i + 1 < NT) {
      if (actNext) convK();
      writeV((i + 1) & 1);
      __syncthreads();
    }
    actCur = actNext;
  }

  // ---- epilogue: cross-half l-sum, redistribute rcp to C rows, store ----
  float tot = lsum + __shfl_xor(lsum, 32, 64);
  float rcp = 1.0f / tot;              // valid for query lo+ql
  float rr[16];
  #pragma unroll
  for (int r = 0; r < 16; ++r)
    rr[r] = __shfl(rcp, ((r & 3) + 8 * (r >> 2)) + 4 * h, 64);
  #pragma unroll
  for (int db = 0; db < 2; ++db)
    #pragma unroll
    for (int r = 0; r < 16; ++r) {
      const int row = lo + ((r & 3) + 8 * (r >> 2)) + 4 * h;
      Og[base + (size_t)row * DH + 32 * db + ql] = acc[db][r] * rr[r];
    }
}

extern "C" void kernel_launch(void* const* d_in, const int* in_sizes, int n_in,
                              void* d_out, int out_size, void* d_ws, size_t ws_size,
                              hipStream_t stream) {
  const float* Q = (const float*)d_in[0];
  const float* K = (const float*)d_in[1];
  const float* V = (const float*)d_in[2];
  float* O = (float*)d_out;
  (void)d_ws; (void)ws_size;

  swa_attn_fused<<<dim3(SEQ / QT, NBATCH * NHEAD), dim3(256), 0, stream>>>(Q, K, V, O);
}

// Round 4
// 111.399 us; speedup vs baseline: 1.1082x; 1.1082x over previous
//
#include <hip/hip_runtime.h>

// Sliding-window causal attention, B=2 H=8 S=4096 D=64, window=512.
// R9: R7 structure (proven best: 32-query waves, swapped QK^T, in-register
//     P transpose, 2-tile-deep K/V triple-buffered prefetch, never-drain
//     vmcnt, XCD swizzle, exp2 fold) plus:
//  + s_setprio(1) around QK and PV MFMA clusters (T5).
//  + prep XCD remap so each tile is prepped on the XCD that consumes it
//    (attn's global_load_lds then hits the local 4 MB L2, not cross-die LLC).

#define NBATCH 2
#define NHEAD  8
#define SEQ    4096
#define DH     64
#define WIN    512
#define QT     128
#define KT     64

typedef __attribute__((ext_vector_type(4)))  float f32x4;
typedef __attribute__((ext_vector_type(16))) float f32x16;
typedef __attribute__((ext_vector_type(8)))  short bf16x8;
typedef unsigned short ushort_t;

__device__ __forceinline__ unsigned short f2bf(float f) {
  unsigned u = __builtin_bit_cast(unsigned, f);
  u += 0x7fffu + ((u >> 16) & 1u);
  return (unsigned short)(u >> 16);
}

__device__ __forceinline__ unsigned pkbf16(float a, float b) {
  unsigned d;
  asm("v_cvt_pk_bf16_f32 %0, %1, %2" : "=v"(d) : "v"(a), "v"(b));
  return d;
}

#define GLD16(gp, lp)                                                          \
  __builtin_amdgcn_global_load_lds(                                            \
      (const __attribute__((address_space(1))) unsigned int*)(gp),             \
      (__attribute__((address_space(3))) unsigned int*)(lp), 16, 0, 0)

// ---------------------------------------------------------------------------
// Prep: swizzled 8 KB 64x64 tile images. (row,blk) -> row*128 + ((blk^(row&7))<<4)
// K image: row = key, blk = d/8.   V image: row = d, blk = key/8.
// Block remap: XCD x (= flat%8) preps bh in {2x, 2x+1} — the same panels the
// attention kernel's swizzle assigns to XCD x, so tiles are written into the
// L2 that will read them.
// ---------------------------------------------------------------------------
__global__ __launch_bounds__(256) void prep_kernel(
    const float* __restrict__ Kg, const float* __restrict__ Vg,
    ushort_t* __restrict__ Kw, ushort_t* __restrict__ Vw)
{
  const int flat = blockIdx.y * gridDim.x + blockIdx.x;   // 0..1023
  const int j = flat >> 3;                                // 0..127
  const int bh = 2 * (flat & 7) + (j >> 6);               // XCD-matched panel
  const int kt = j & 63;

  const size_t gbase = (size_t)bh * SEQ * DH + (size_t)kt * KT * DH;
  const size_t tbyte = ((size_t)bh * 64 + kt) * 8192;
  const int t = threadIdx.x;

  __shared__ float Vs[64][65];

  #pragma unroll
  for (int c = 0; c < 2; ++c) {
    int u = t + 256 * c, row = u >> 3, blk = u & 7;
    const float* src = Kg + gbase + row * DH + blk * 8;
    float4 a = *(const float4*)src;
    float4 b = *(const float4*)(src + 4);
    union { unsigned short us[8]; uint4 q; } o;
    o.us[0]=f2bf(a.x); o.us[1]=f2bf(a.y); o.us[2]=f2bf(a.z); o.us[3]=f2bf(a.w);
    o.us[4]=f2bf(b.x); o.us[5]=f2bf(b.y); o.us[6]=f2bf(b.z); o.us[7]=f2bf(b.w);
    *(uint4*)((char*)Kw + tbyte + row * 128 + ((blk ^ (row & 7)) << 4)) = o.q;
  }

  #pragma unroll
  for (int i = 0; i < 4; ++i) {
    int e = t + 256 * i, row = e >> 4, c4 = (e & 15) * 4;
    float4 v = *(const float4*)(Vg + gbase + row * DH + c4);
    Vs[row][c4 + 0] = v.x; Vs[row][c4 + 1] = v.y;
    Vs[row][c4 + 2] = v.z; Vs[row][c4 + 3] = v.w;
  }
  __syncthreads();

  #pragma unroll
  for (int c = 0; c < 2; ++c) {
    int u = t + 256 * c, d = u >> 3, blk = u & 7;
    union { unsigned short us[8]; uint4 q; } o;
    #pragma unroll
    for (int jj = 0; jj < 8; ++jj) o.us[jj] = f2bf(Vs[blk * 8 + jj][d]);
    *(uint4*)((char*)Vw + tbyte + d * 128 + ((blk ^ (d & 7)) << 4)) = o.q;
  }
}

// ---------------------------------------------------------------------------
// Attention: one block = 128 queries of one (b,h); 4 waves x 32 queries.
// ---------------------------------------------------------------------------
__global__ __launch_bounds__(256, 2) void swa_attn_kernel(
    const float* __restrict__ Qg, const ushort_t* __restrict__ Kw,
    const ushort_t* __restrict__ Vw, float* __restrict__ Og)
{
  // bijective XCD swizzle: 512 blocks, 8 XCDs, 64 blocks/XCD = 2 bh panels.
  const int flat = blockIdx.y * gridDim.x + blockIdx.x;      // 0..511
  const int swz  = (flat & 7) * 64 + (flat >> 3);
  const int qt = swz & 31, bh = swz >> 5;

  const int q0 = qt * QT;
  const size_t base = (size_t)bh * SEQ * DH;
  const int t = threadIdx.x, w = t >> 6, l = t & 63;
  const int ql = l & 31, h = l >> 5;

  __shared__ ushort_t Ks[3][4096];   // 24 KB, triple buffer
  __shared__ ushort_t Vt[3][4096];   // 24 KB, triple buffer
  // total 48 KB -> 2 blocks/CU (grid is exactly 2/CU)

  const size_t tile0 = ((size_t)bh * 64) * 8192;
  const int ldoff = w * 2048;        // this wave's 2 KB slice (wave-uniform)

  auto issueK = [&](int b, int kt) {
    const char* g = (const char*)Kw + tile0 + (size_t)kt * 8192 + ldoff;
    char* lp = (char*)&Ks[b][0] + ldoff;
    GLD16(g + l * 16, lp);
    GLD16(g + 1024 + l * 16, lp + 1024);
  };
  auto issueV = [&](int b, int kt) {
    const char* g = (const char*)Vw + tile0 + (size_t)kt * 8192 + ldoff;
    char* lp = (char*)&Vt[b][0] + ldoff;
    GLD16(g + l * 16, lp);
    GLD16(g + 1024 + l * 16, lp + 1024);
  };

  const int kt_hi = 2 * qt + 1;
  const int kt_lo = (2 * qt - 8 > 0) ? (2 * qt - 8) : 0;
  const int NT = kt_hi - kt_lo + 1;   // >= 2 always

  const int lo = q0 + 32 * w;   // this wave's min query row
  const int hi = lo + 31;       // max query row

  // ---- Q loads FIRST (oldest in vmcnt queue) ----
  const float* qrow = Qg + base + (size_t)(lo + ql) * DH;
  float4 qa[4], qb[4];
  #pragma unroll
  for (int tf = 0; tf < 4; ++tf) {
    qa[tf] = *(const float4*)(qrow + 16 * tf + 8 * h);
    qb[tf] = *(const float4*)(qrow + 16 * tf + 8 * h + 4);
  }
  issueK(0, kt_hi);
  issueV(0, kt_hi);

  // Q as B-frags, prescaled by (1/8)*log2(e) so softmax is raw v_exp_f32.
  const float QS = 0.125f * 1.44269504088896f;
  bf16x8 aq[4];
  #pragma unroll
  for (int tf = 0; tf < 4; ++tf) {
    union { unsigned short us[8]; bf16x8 v; } u;
    u.us[0]=f2bf(qa[tf].x*QS); u.us[1]=f2bf(qa[tf].y*QS);
    u.us[2]=f2bf(qa[tf].z*QS); u.us[3]=f2bf(qa[tf].w*QS);
    u.us[4]=f2bf(qb[tf].x*QS); u.us[5]=f2bf(qb[tf].y*QS);
    u.us[6]=f2bf(qb[tf].z*QS); u.us[7]=f2bf(qb[tf].w*QS);
    aq[tf] = u.v;
  }

  // second prefetch tile (2-deep pipeline)
  issueK(1, kt_hi - 1);
  issueV(1, kt_hi - 1);

  f32x16 acc[2];
  #pragma unroll
  for (int db = 0; db < 2; ++db)
    #pragma unroll
    for (int r = 0; r < 16; ++r) acc[db][r] = 0.0f;
  float lsum = 0.0f;

  int cur = 0;  // i % 3
  for (int i = 0; i < NT; ++i) {
    const int kt = kt_hi - i;
    const int k0 = kt * KT;

    // Drain tile i's K+V (4 oldest); leave tile i+1's 4 loads in flight.
    if (i < NT - 1) {
      __asm__ __volatile__("s_waitcnt vmcnt(4)\n\ts_barrier" ::: "memory");
    } else {
      __asm__ __volatile__("s_waitcnt vmcnt(0)\n\ts_barrier" ::: "memory");
    }
    // Issue tile i+2 AFTER the barrier: buffer (i+2)%3 == (i-1)%3 was fully
    // consumed by all waves before they reached this barrier.
    if (i + 2 < NT) {
      int nxt = cur + 2; if (nxt >= 3) nxt -= 3;
      issueK(nxt, kt - 2);
      issueV(nxt, kt - 2);
    }

    // ---- per-wave skip of fully-masked tiles (wave-uniform branch) ----
    const bool active = (k0 <= hi) && (k0 + KT - 1 >= lo - (WIN - 1));
    if (active) {
      const char* kbuf = (const char*)&Ks[cur][0];
      const char* vbuf = (const char*)&Vt[cur][0];

      // ---- S^T = K Q^T : lane holds P[k = 32*kb + a(r) + 4h][q = lo+ql] ----
      f32x16 p[2];
      __builtin_amdgcn_s_setprio(1);
      #pragma unroll
      for (int kb = 0; kb < 2; ++kb) {
        const int krow = 32 * kb + ql;
        const int ksz = krow & 7;
        f32x16 c;
        #pragma unroll
        for (int r = 0; r < 16; ++r) c[r] = 0.0f;
        #pragma unroll
        for (int tf = 0; tf < 4; ++tf) {
          bf16x8 ka = *(const bf16x8*)(kbuf + krow * 128 + (((2*tf + h) ^ ksz) << 4));
          c = __builtin_amdgcn_mfma_f32_32x32x16_bf16(ka, aq[tf], c, 0, 0, 0);
        }
        p[kb] = c;
      }
      __builtin_amdgcn_s_setprio(0);

      // ---- exp2 (m=0 fixed shift, exact) + tree-reduced l-sum ----
      const int dbase = k0 - (lo + ql) + 4 * h;
      const bool needmask = (k0 + KT - 1 > lo) || (k0 < hi - (WIN - 1));
      float ps0 = 0.f, ps1 = 0.f, ps2 = 0.f, ps3 = 0.f;
      if (needmask) {
        #pragma unroll
        for (int kb = 0; kb < 2; ++kb)
          #pragma unroll
          for (int r = 0; r < 16; ++r) {
            const int dji = dbase + 32 * kb + ((r & 3) + 8 * (r >> 2));
            float s = ((unsigned)(dji + (WIN - 1)) <= (unsigned)(WIN - 1))
                          ? p[kb][r] : -1e30f;
            float e = __builtin_amdgcn_exp2f(s);
            p[kb][r] = e;
            if ((r & 3) == 0) ps0 += e;
            else if ((r & 3) == 1) ps1 += e;
            else if ((r & 3) == 2) ps2 += e;
            else ps3 += e;
          }
      } else {
        #pragma unroll
        for (int kb = 0; kb < 2; ++kb)
          #pragma unroll
          for (int r = 0; r < 16; ++r) {
            float e = __builtin_amdgcn_exp2f(p[kb][r]);
            p[kb][r] = e;
            if ((r & 3) == 0) ps0 += e;
            else if ((r & 3) == 1) ps1 += e;
            else if ((r & 3) == 2) ps2 += e;
            else ps3 += e;
          }
      }
      lsum += (ps0 + ps1) + (ps2 + ps3);

      // ---- in-register P transpose -> A-frags, fused with O += P V ----
      __builtin_amdgcn_s_setprio(1);
      #pragma unroll
      for (int kb = 0; kb < 2; ++kb) {
        #pragma unroll
        for (int b = 0; b < 2; ++b) {
          unsigned x0 = pkbf16(p[kb][8*b+0], p[kb][8*b+1]);
          unsigned x1 = pkbf16(p[kb][8*b+2], p[kb][8*b+3]);
          unsigned y0 = pkbf16(p[kb][8*b+4], p[kb][8*b+5]);
          unsigned y1 = pkbf16(p[kb][8*b+6], p[kb][8*b+7]);
          asm("v_permlane32_swap_b32 %0, %1" : "+v"(x0), "+v"(y0));
          asm("v_permlane32_swap_b32 %0, %1" : "+v"(x1), "+v"(y1));
          union { unsigned u[4]; bf16x8 v; } fa;
          fa.u[0] = x0; fa.u[1] = x1; fa.u[2] = y0; fa.u[3] = y1;
          const int ks = 2 * kb + b;   // k-slice 16*ks .. 16*ks+15
          #pragma unroll
          for (int db = 0; db < 2; ++db) {
            const int vrow = 32 * db + ql;
            bf16x8 vb = *(const bf16x8*)(vbuf + vrow * 128 +
                                         (((2*ks + h) ^ (vrow & 7)) << 4));
            acc[db] = __builtin_amdgcn_mfma_f32_32x32x16_bf16(fa.v, vb, acc[db], 0, 0, 0);
          }
        }
      }
      __builtin_amdgcn_s_setprio(0);
    }

    cur += 1; if (cur == 3) cur = 0;
  }

  // ---- epilogue: cross-half l-sum, redistribute rcp to C rows, store ----
  float tot = lsum + __shfl_xor(lsum, 32, 64);
  float rcp = 1.0f / tot;              // valid for query lo+ql
  float rr[16];
  #pragma unroll
  for (int r = 0; r < 16; ++r)
    rr[r] = __shfl(rcp, ((r & 3) + 8 * (r >> 2)) + 4 * h, 64);
  #pragma unroll
  for (int db = 0; db < 2; ++db)
    #pragma unroll
    for (int r = 0; r < 16; ++r) {
      const int row = lo + ((r & 3) + 8 * (r >> 2)) + 4 * h;
      Og[base + (size_t)row * DH + 32 * db + ql] = acc[db][r] * rr[r];
    }
}

// ---------------------------------------------------------------------------
// Fallback (fp32 inputs, self-contained) if workspace too small.
// ---------------------------------------------------------------------------
#define LDP 72
__global__ __launch_bounds__(256) void swa_attn_fallback(
    const float* __restrict__ Qg, const float* __restrict__ Kg,
    const float* __restrict__ Vg, float* __restrict__ Og)
{
  const int qt = blockIdx.x, bh = blockIdx.y;
  const int q0 = qt * 64;
  const size_t base = (size_t)bh * SEQ * DH;
  const int t = threadIdx.x, w = t >> 6, l = t & 63, quad = l >> 4, lc = l & 15;

  __shared__ unsigned short Qs[64][LDP];
  __shared__ unsigned short KsF[64][LDP];
  __shared__ unsigned short VtF[DH][LDP];
  __shared__ unsigned short PsF[4][16][LDP];

  {
    const float* src = Qg + base + (size_t)q0 * DH;
    #pragma unroll
    for (int i = 0; i < 4; ++i) {
      int e = t + 256 * i, row = e >> 4, d4 = (e & 15) * 4;
      float4 v = *(const float4*)(src + row * DH + d4);
      ushort4 o; o.x=f2bf(v.x*0.125f); o.y=f2bf(v.y*0.125f); o.z=f2bf(v.z*0.125f); o.w=f2bf(v.w*0.125f);
      *(ushort4*)&Qs[row][d4] = o;
    }
  }
  __syncthreads();
  bf16x8 aq0 = *(const bf16x8*)&Qs[16*w+lc][0 + 8*quad];
  bf16x8 aq1 = *(const bf16x8*)&Qs[16*w+lc][32 + 8*quad];

  float lsum[4]; f32x4 acc_o[4];
  #pragma unroll
  for (int r = 0; r < 4; ++r) lsum[r] = 0.0f;
  #pragma unroll
  for (int g = 0; g < 4; ++g) { acc_o[g][0]=0.f; acc_o[g][1]=0.f; acc_o[g][2]=0.f; acc_o[g][3]=0.f; }
  const int kt_lo = (qt - 8 > 0) ? (qt - 8) : 0;

  for (int kt = qt; kt >= kt_lo; --kt) {
    const int k0 = kt * 64;
    __syncthreads();
    {
      const float* srcK = Kg + base + (size_t)k0 * DH;
      const float* srcV = Vg + base + (size_t)k0 * DH;
      #pragma unroll
      for (int i = 0; i < 4; ++i) {
        int e = t + 256 * i, row = e >> 4, d4 = (e & 15) * 4;
        float4 kv = *(const float4*)(srcK + row * DH + d4);
        ushort4 ko; ko.x=f2bf(kv.x); ko.y=f2bf(kv.y); ko.z=f2bf(kv.z); ko.w=f2bf(kv.w);
        *(ushort4*)&KsF[row][d4] = ko;
        float4 vv = *(const float4*)(srcV + row * DH + d4);
        VtF[d4+0][row]=f2bf(vv.x); VtF[d4+1][row]=f2bf(vv.y);
        VtF[d4+2][row]=f2bf(vv.z); VtF[d4+3][row]=f2bf(vv.w);
      }
    }
    __syncthreads();

    f32x4 sc[4];
    #pragma unroll
    for (int g = 0; g < 4; ++g) {
      bf16x8 b0 = *(const bf16x8*)&KsF[16*g+lc][0 + 8*quad];
      bf16x8 b1 = *(const bf16x8*)&KsF[16*g+lc][32 + 8*quad];
      f32x4 c; c[0]=0.f; c[1]=0.f; c[2]=0.f; c[3]=0.f;
      c = __builtin_amdgcn_mfma_f32_16x16x32_bf16(aq0, b0, c, 0, 0, 0);
      c = __builtin_amdgcn_mfma_f32_16x16x32_bf16(aq1, b1, c, 0, 0, 0);
      sc[g] = c;
    }
    const int dbase = (k0 + lc) - (q0 + 16*w + 4*quad);
    #pragma unroll
    for (int g = 0; g < 4; ++g)
      #pragma unroll
      for (int r = 0; r < 4; ++r) {
        int dji = dbase + 16*g - r;
        float s = sc[g][r];
        s = (dji <= 0 && dji >= -(WIN-1)) ? s : -1e30f;
        float e = __expf(s);
        lsum[r] += e;
        PsF[w][4*quad+r][16*g+lc] = f2bf(e);
      }
    __asm__ __volatile__("s_waitcnt lgkmcnt(0)" ::: "memory");
    bf16x8 pa0 = *(const bf16x8*)&PsF[w][lc][0 + 8*quad];
    bf16x8 pa1 = *(const bf16x8*)&PsF[w][lc][32 + 8*quad];
    #pragma unroll
    for (int gn = 0; gn < 4; ++gn) {
      bf16x8 vb0 = *(const bf16x8*)&VtF[16*gn+lc][0 + 8*quad];
      bf16x8 vb1 = *(const bf16x8*)&VtF[16*gn+lc][32 + 8*quad];
      f32x4 c = acc_o[gn];
      c = __builtin_amdgcn_mfma_f32_16x16x32_bf16(pa0, vb0, c, 0, 0, 0);
      c = __builtin_amdgcn_mfma_f32_16x16x32_bf16(pa1, vb1, c, 0, 0, 0);
      acc_o[gn] = c;
    }
  }
  #pragma unroll
  for (int off = 1; off < 16; off <<= 1)
    #pragma unroll
    for (int r = 0; r < 4; ++r)
      lsum[r] += __shfl_xor(lsum[r], off, 64);
  #pragma unroll
  for (int gn = 0; gn < 4; ++gn)
    #pragma unroll
    for (int r = 0; r < 4; ++r) {
      int row = q0 + 16*w + 4*quad + r;
      Og[base + (size_t)row * DH + 16*gn + lc] = acc_o[gn][r] / lsum[r];
    }
}

extern "C" void kernel_launch(void* const* d_in, const int* in_sizes, int n_in,
                              void* d_out, int out_size, void* d_ws, size_t ws_size,
                              hipStream_t stream) {
  const float* Q = (const float*)d_in[0];
  const float* K = (const float*)d_in[1];
  const float* V = (const float*)d_in[2];
  float* O = (float*)d_out;

  const size_t kbytes = (size_t)NBATCH * NHEAD * SEQ * DH * 2;   // 8 MB
  if (ws_size >= 2 * kbytes) {
    ushort_t* Kw = (ushort_t*)d_ws;
    ushort_t* Vw = (ushort_t*)((char*)d_ws + kbytes);
    prep_kernel<<<dim3(SEQ / KT, NBATCH * NHEAD), dim3(256), 0, stream>>>(K, V, Kw, Vw);
    swa_attn_kernel<<<dim3(SEQ / QT, NBATCH * NHEAD), dim3(256), 0, stream>>>(Q, Kw, Vw, O);
  } else {
    swa_attn_fallback<<<dim3(SEQ / 64, NBATCH * NHEAD), dim3(256), 0, stream>>>(Q, K, V, O);
  }
}

// Round 5
// 105.536 us; speedup vs baseline: 1.1698x; 1.0556x over previous
//
#include <hip/hip_runtime.h>

// Sliding-window causal attention, B=2 H=8 S=4096 D=64, window=512.
// R10: fused single kernel, v2 (fixes R8's failure mode).
//   Both K and V staged through double-buffered swizzled LDS images from
//   fp32 global (coalesced float4/dword loads -> cvt_pk -> ds_write_b128),
//   register-staged one tile ahead; sched_barrier(0) pins load issue so the
//   compiler cannot sink the prefetch (R8's bug). One barrier per tile.
//   Compute core identical to verified R7/R9: 32-query waves, swapped QK^T,
//   in-register P transpose (cvt_pk+permlane32_swap), m=0 exp2 softmax,
//   setprio around MFMA clusters, bijective XCD swizzle.
//   No prep kernel, no workspace, no inter-kernel gap.

#define NBATCH 2
#define NHEAD  8
#define SEQ    4096
#define DH     64
#define WIN    512
#define QT     128
#define KT     64

typedef __attribute__((ext_vector_type(4)))  float f32x4;
typedef __attribute__((ext_vector_type(16))) float f32x16;
typedef __attribute__((ext_vector_type(8)))  short bf16x8;
typedef unsigned short ushort_t;

__device__ __forceinline__ unsigned short f2bf(float f) {
  unsigned u = __builtin_bit_cast(unsigned, f);
  u += 0x7fffu + ((u >> 16) & 1u);
  return (unsigned short)(u >> 16);
}

__device__ __forceinline__ unsigned pkbf16(float a, float b) {
  unsigned d;
  asm("v_cvt_pk_bf16_f32 %0, %1, %2" : "=v"(d) : "v"(a), "v"(b));
  return d;
}

// ---------------------------------------------------------------------------
// Fused attention: one block = 128 queries of one (b,h); 4 waves x 32 queries.
// LDS images (per tile, 8 KB each):
//   K: row = key (128 B), d-block blk=d/8 at byte ((blk ^ (key&7))<<4)
//   V: row = d  (128 B), key-block blk=key/8 at byte ((blk ^ (d&7))<<4)
// ---------------------------------------------------------------------------
__global__ __launch_bounds__(256, 2) void swa_attn_fused(
    const float* __restrict__ Qg, const float* __restrict__ Kg,
    const float* __restrict__ Vg, float* __restrict__ Og)
{
  // bijective XCD swizzle: 512 blocks, 8 XCDs, 64 blocks/XCD = 2 bh panels.
  const int flat = blockIdx.y * gridDim.x + blockIdx.x;      // 0..511
  const int swz  = (flat & 7) * 64 + (flat >> 3);
  const int qt = swz & 31, bh = swz >> 5;

  const int q0 = qt * QT;
  const size_t base = (size_t)bh * SEQ * DH;
  const int t = threadIdx.x, w = t >> 6, l = t & 63;
  const int ql = l & 31, h = l >> 5;

  __shared__ ushort_t KsL[2][4096];   // 16 KB double buffer
  __shared__ ushort_t VtL[2][4096];   // 16 KB double buffer  (32 KB total)

  const int kt_hi = 2 * qt + 1;
  const int kt_lo = (2 * qt - 8 > 0) ? (2 * qt - 8) : 0;
  const int NT = kt_hi - kt_lo + 1;   // 2..10

  const int lo = q0 + 32 * w;   // this wave's min query row
  const int hi = lo + 31;       // max query row

  // ---- staging state (held in registers across one compute phase) ----
  float4 kst[4];   // K: thread -> key = t>>2, d = 16*(t&3) .. +15
  float  vst[16];  // V: thread -> d-column l, keys 16w .. 16w+15

  auto stageLoad = [&](int kt) {
    const float* kp = Kg + base + (size_t)(kt * KT + (t >> 2)) * DH + (t & 3) * 16;
    kst[0] = *(const float4*)(kp);
    kst[1] = *(const float4*)(kp + 4);
    kst[2] = *(const float4*)(kp + 8);
    kst[3] = *(const float4*)(kp + 12);
    const float* vp = Vg + base + (size_t)(kt * KT + 16 * w) * DH + l;
    #pragma unroll
    for (int j = 0; j < 16; ++j) vst[j] = vp[j * DH];
  };
  auto stageWrite = [&](int buf) {
    const int key = t >> 2, dseg = t & 3;
    char* kb = (char*)&KsL[buf][0] + key * 128;
    #pragma unroll
    for (int m = 0; m < 2; ++m) {
      union { unsigned u[4]; uint4 q; } o;
      float4 c0 = kst[2 * m], c1 = kst[2 * m + 1];
      o.u[0] = pkbf16(c0.x, c0.y); o.u[1] = pkbf16(c0.z, c0.w);
      o.u[2] = pkbf16(c1.x, c1.y); o.u[3] = pkbf16(c1.z, c1.w);
      *(uint4*)(kb + (((2 * dseg + m) ^ (key & 7)) << 4)) = o.q;
    }
    char* vb = (char*)&VtL[buf][0] + l * 128;
    #pragma unroll
    for (int jj = 0; jj < 2; ++jj) {
      union { unsigned u[4]; uint4 q; } o;
      o.u[0] = pkbf16(vst[8 * jj + 0], vst[8 * jj + 1]);
      o.u[1] = pkbf16(vst[8 * jj + 2], vst[8 * jj + 3]);
      o.u[2] = pkbf16(vst[8 * jj + 4], vst[8 * jj + 5]);
      o.u[3] = pkbf16(vst[8 * jj + 6], vst[8 * jj + 7]);
      *(uint4*)(vb + (((2 * w + jj) ^ (l & 7)) << 4)) = o.q;
    }
  };

  // ---- Q loads FIRST, tile-0 staging loads immediately after ----
  const float* qrow = Qg + base + (size_t)(lo + ql) * DH;
  float4 qa[4], qb[4];
  #pragma unroll
  for (int tf = 0; tf < 4; ++tf) {
    qa[tf] = *(const float4*)(qrow + 16 * tf + 8 * h);
    qb[tf] = *(const float4*)(qrow + 16 * tf + 8 * h + 4);
  }
  stageLoad(kt_hi);
  __builtin_amdgcn_sched_barrier(0);

  // Q as B-frags, prescaled by (1/8)*log2(e) so softmax is raw v_exp_f32.
  const float QS = 0.125f * 1.44269504088896f;
  bf16x8 aq[4];
  #pragma unroll
  for (int tf = 0; tf < 4; ++tf) {
    union { unsigned short us[8]; bf16x8 v; } u;
    u.us[0]=f2bf(qa[tf].x*QS); u.us[1]=f2bf(qa[tf].y*QS);
    u.us[2]=f2bf(qa[tf].z*QS); u.us[3]=f2bf(qa[tf].w*QS);
    u.us[4]=f2bf(qb[tf].x*QS); u.us[5]=f2bf(qb[tf].y*QS);
    u.us[6]=f2bf(qb[tf].z*QS); u.us[7]=f2bf(qb[tf].w*QS);
    aq[tf] = u.v;
  }

  // commit tile 0 image, then issue tile 1 loads (1-deep pipeline)
  stageWrite(0);
  if (NT > 1) {
    stageLoad(kt_hi - 1);
    __builtin_amdgcn_sched_barrier(0);
  }
  __syncthreads();

  f32x16 acc[2];
  #pragma unroll
  for (int db = 0; db < 2; ++db)
    #pragma unroll
    for (int r = 0; r < 16; ++r) acc[db][r] = 0.0f;
  float lsum = 0.0f;

  for (int i = 0; i < NT; ++i) {
    const int kt = kt_hi - i;
    const int k0 = kt * KT;

    // ---- per-wave skip of fully-masked tiles (wave-uniform branch) ----
    const bool active = (k0 <= hi) && (k0 + KT - 1 >= lo - (WIN - 1));
    if (active) {
      const char* kbuf = (const char*)&KsL[i & 1][0];
      const char* vbuf = (const char*)&VtL[i & 1][0];

      // ---- S^T = K Q^T : lane holds P[k = 32*kb + a(r) + 4h][q = lo+ql] ----
      f32x16 p[2];
      __builtin_amdgcn_s_setprio(1);
      #pragma unroll
      for (int kb = 0; kb < 2; ++kb) {
        const int krow = 32 * kb + ql;
        const int ksz = krow & 7;
        f32x16 c;
        #pragma unroll
        for (int r = 0; r < 16; ++r) c[r] = 0.0f;
        #pragma unroll
        for (int tf = 0; tf < 4; ++tf) {
          bf16x8 ka = *(const bf16x8*)(kbuf + krow * 128 + (((2*tf + h) ^ ksz) << 4));
          c = __builtin_amdgcn_mfma_f32_32x32x16_bf16(ka, aq[tf], c, 0, 0, 0);
        }
        p[kb] = c;
      }
      __builtin_amdgcn_s_setprio(0);

      // ---- exp2 (m=0 fixed shift, exact) + tree-reduced l-sum ----
      const int dbase = k0 - (lo + ql) + 4 * h;
      const bool needmask = (k0 + KT - 1 > lo) || (k0 < hi - (WIN - 1));
      float ps0 = 0.f, ps1 = 0.f, ps2 = 0.f, ps3 = 0.f;
      if (needmask) {
        #pragma unroll
        for (int kb = 0; kb < 2; ++kb)
          #pragma unroll
          for (int r = 0; r < 16; ++r) {
            const int dji = dbase + 32 * kb + ((r & 3) + 8 * (r >> 2));
            float s = ((unsigned)(dji + (WIN - 1)) <= (unsigned)(WIN - 1))
                          ? p[kb][r] : -1e30f;
            float e = __builtin_amdgcn_exp2f(s);
            p[kb][r] = e;
            if ((r & 3) == 0) ps0 += e;
            else if ((r & 3) == 1) ps1 += e;
            else if ((r & 3) == 2) ps2 += e;
            else ps3 += e;
          }
      } else {
        #pragma unroll
        for (int kb = 0; kb < 2; ++kb)
          #pragma unroll
          for (int r = 0; r < 16; ++r) {
            float e = __builtin_amdgcn_exp2f(p[kb][r]);
            p[kb][r] = e;
            if ((r & 3) == 0) ps0 += e;
            else if ((r & 3) == 1) ps1 += e;
            else if ((r & 3) == 2) ps2 += e;
            else ps3 += e;
          }
      }
      lsum += (ps0 + ps1) + (ps2 + ps3);

      // ---- in-register P transpose -> A-frags, fused with O += P V ----
      __builtin_amdgcn_s_setprio(1);
      #pragma unroll
      for (int kb = 0; kb < 2; ++kb) {
        #pragma unroll
        for (int b = 0; b < 2; ++b) {
          unsigned x0 = pkbf16(p[kb][8*b+0], p[kb][8*b+1]);
          unsigned x1 = pkbf16(p[kb][8*b+2], p[kb][8*b+3]);
          unsigned y0 = pkbf16(p[kb][8*b+4], p[kb][8*b+5]);
          unsigned y1 = pkbf16(p[kb][8*b+6], p[kb][8*b+7]);
          asm("v_permlane32_swap_b32 %0, %1" : "+v"(x0), "+v"(y0));
          asm("v_permlane32_swap_b32 %0, %1" : "+v"(x1), "+v"(y1));
          union { unsigned u[4]; bf16x8 v; } fa;
          fa.u[0] = x0; fa.u[1] = x1; fa.u[2] = y0; fa.u[3] = y1;
          const int ks = 2 * kb + b;   // k-slice 16*ks .. 16*ks+15
          #pragma unroll
          for (int db = 0; db < 2; ++db) {
            const int vrow = 32 * db + ql;
            bf16x8 vb = *(const bf16x8*)(vbuf + vrow * 128 +
                                         (((2*ks + h) ^ (vrow & 7)) << 4));
            acc[db] = __builtin_amdgcn_mfma_f32_32x32x16_bf16(fa.v, vb, acc[db], 0, 0, 0);
          }
        }
      }
      __builtin_amdgcn_s_setprio(0);
    }

    // ---- commit tile i+1's image; issue tile i+2's loads; one barrier ----
    if (i + 1 < NT) {
      stageWrite((i + 1) & 1);        // waits staged-reg vmcnt automatically
      if (i + 2 < NT) {
        stageLoad(kt - 2);            // regs free after cvt consumed them
        __builtin_amdgcn_sched_barrier(0);   // pin issue point (R8 fix)
      }
      __syncthreads();
    }
  }

  // ---- epilogue: cross-half l-sum, redistribute rcp to C rows, store ----
  float tot = lsum + __shfl_xor(lsum, 32, 64);
  float rcp = 1.0f / tot;              // valid for query lo+ql
  float rr[16];
  #pragma unroll
  for (int r = 0; r < 16; ++r)
    rr[r] = __shfl(rcp, ((r & 3) + 8 * (r >> 2)) + 4 * h, 64);
  #pragma unroll
  for (int db = 0; db < 2; ++db)
    #pragma unroll
    for (int r = 0; r < 16; ++r) {
      const int row = lo + ((r & 3) + 8 * (r >> 2)) + 4 * h;
      Og[base + (size_t)row * DH + 32 * db + ql] = acc[db][r] * rr[r];
    }
}

extern "C" void kernel_launch(void* const* d_in, const int* in_sizes, int n_in,
                              void* d_out, int out_size, void* d_ws, size_t ws_size,
                              hipStream_t stream) {
  const float* Q = (const float*)d_in[0];
  const float* K = (const float*)d_in[1];
  const float* V = (const float*)d_in[2];
  float* O = (float*)d_out;
  (void)d_ws; (void)ws_size;

  swa_attn_fused<<<dim3(SEQ / QT, NBATCH * NHEAD), dim3(256), 0, stream>>>(Q, K, V, O);
}

// Round 6
// 104.854 us; speedup vs baseline: 1.1774x; 1.0065x over previous
//
#include <hip/hip_runtime.h>

// Sliding-window causal attention, B=2 H=8 S=4096 D=64, window=512.
// R11: R10 fused structure, QT 128->256 (8 waves x 32 q, 512 threads,
//   grid=256 = 1 block/CU). Same verified compute core (swapped QK^T,
//   in-register P transpose, m=0 exp2 softmax, setprio, XCD swizzle).
//   Staged tile-phases per CU drop 20->12: -40% staging traffic/barriers;
//   per-thread staging halves (512 threads per tile); K and V LDS writes
//   both bank-conflict-free (XOR covers banks 0..31 per 128B slice).

#define NBATCH 2
#define NHEAD  8
#define SEQ    4096
#define DH     64
#define WIN    512
#define QT     256
#define KT     64

typedef __attribute__((ext_vector_type(4)))  float f32x4;
typedef __attribute__((ext_vector_type(16))) float f32x16;
typedef __attribute__((ext_vector_type(8)))  short bf16x8;
typedef unsigned short ushort_t;

__device__ __forceinline__ unsigned short f2bf(float f) {
  unsigned u = __builtin_bit_cast(unsigned, f);
  u += 0x7fffu + ((u >> 16) & 1u);
  return (unsigned short)(u >> 16);
}

__device__ __forceinline__ unsigned pkbf16(float a, float b) {
  unsigned d;
  asm("v_cvt_pk_bf16_f32 %0, %1, %2" : "=v"(d) : "v"(a), "v"(b));
  return d;
}

// ---------------------------------------------------------------------------
// Fused attention: one block = 256 queries of one (b,h); 8 waves x 32 queries.
// LDS images (per tile, 8 KB each):
//   K: row = key (128 B), d-block blk=d/8 at byte ((blk ^ (key&7))<<4)
//   V: row = d  (128 B), key-block blk=key/8 at byte ((blk ^ (d&7))<<4)
// ---------------------------------------------------------------------------
__global__ __launch_bounds__(512, 1) void swa_attn_fused(
    const float* __restrict__ Qg, const float* __restrict__ Kg,
    const float* __restrict__ Vg, float* __restrict__ Og)
{
  // bijective XCD swizzle: 256 blocks, 8 XCDs, 32 blocks/XCD = 2 bh panels.
  const int flat = blockIdx.y * gridDim.x + blockIdx.x;      // 0..255
  const int swz  = (flat & 7) * 32 + (flat >> 3);
  const int qt = swz & 15, bh = swz >> 4;

  const int q0 = qt * QT;
  const size_t base = (size_t)bh * SEQ * DH;
  const int t = threadIdx.x, w = t >> 6, l = t & 63;
  const int ql = l & 31, h = l >> 5;

  __shared__ ushort_t KsL[2][4096];   // 16 KB double buffer
  __shared__ ushort_t VtL[2][4096];   // 16 KB double buffer  (32 KB total)

  const int kt_hi = 4 * qt + 3;
  const int kt_lo_raw = (q0 - (WIN - 1)) >> 6;               // floor div ok (q0>=0)
  const int kt_lo = kt_lo_raw > 0 ? kt_lo_raw : 0;
  const int NT = kt_hi - kt_lo + 1;   // 4..12

  const int lo = q0 + 32 * w;   // this wave's min query row
  const int hi = lo + 31;       // max query row

  // ---- staging state (held in registers across one compute phase) ----
  float4 kst[2];   // K: thread -> key = t>>3, d = 8*(t&7) .. +7
  float  vst[8];   // V: thread -> d-column t&63, keys 8*(t>>6) .. +7

  auto stageLoad = [&](int kt) {
    const int key = t >> 3, dseg = t & 7;
    const float* kp = Kg + base + (size_t)(kt * KT + key) * DH + dseg * 8;
    kst[0] = *(const float4*)(kp);
    kst[1] = *(const float4*)(kp + 4);
    const int vd = t & 63, vk0 = (t >> 6) * 8;
    const float* vp = Vg + base + (size_t)(kt * KT + vk0) * DH + vd;
    #pragma unroll
    for (int j = 0; j < 8; ++j) vst[j] = vp[j * DH];
  };
  auto stageWrite = [&](int buf) {
    const int key = t >> 3, dseg = t & 7;
    union { unsigned u[4]; uint4 q; } ok;
    ok.u[0] = pkbf16(kst[0].x, kst[0].y); ok.u[1] = pkbf16(kst[0].z, kst[0].w);
    ok.u[2] = pkbf16(kst[1].x, kst[1].y); ok.u[3] = pkbf16(kst[1].z, kst[1].w);
    *(uint4*)((char*)&KsL[buf][0] + key * 128 + ((dseg ^ (key & 7)) << 4)) = ok.q;
    const int vd = t & 63, vblk = t >> 6;
    union { unsigned u[4]; uint4 q; } ov;
    ov.u[0] = pkbf16(vst[0], vst[1]); ov.u[1] = pkbf16(vst[2], vst[3]);
    ov.u[2] = pkbf16(vst[4], vst[5]); ov.u[3] = pkbf16(vst[6], vst[7]);
    *(uint4*)((char*)&VtL[buf][0] + vd * 128 + ((vblk ^ (vd & 7)) << 4)) = ov.q;
  };

  // ---- Q loads FIRST, tile-0 staging loads immediately after ----
  const float* qrow = Qg + base + (size_t)(lo + ql) * DH;
  float4 qa[4], qb[4];
  #pragma unroll
  for (int tf = 0; tf < 4; ++tf) {
    qa[tf] = *(const float4*)(qrow + 16 * tf + 8 * h);
    qb[tf] = *(const float4*)(qrow + 16 * tf + 8 * h + 4);
  }
  stageLoad(kt_hi);
  __builtin_amdgcn_sched_barrier(0);

  // Q as B-frags, prescaled by (1/8)*log2(e) so softmax is raw v_exp_f32.
  const float QS = 0.125f * 1.44269504088896f;
  bf16x8 aq[4];
  #pragma unroll
  for (int tf = 0; tf < 4; ++tf) {
    union { unsigned short us[8]; bf16x8 v; } u;
    u.us[0]=f2bf(qa[tf].x*QS); u.us[1]=f2bf(qa[tf].y*QS);
    u.us[2]=f2bf(qa[tf].z*QS); u.us[3]=f2bf(qa[tf].w*QS);
    u.us[4]=f2bf(qb[tf].x*QS); u.us[5]=f2bf(qb[tf].y*QS);
    u.us[6]=f2bf(qb[tf].z*QS); u.us[7]=f2bf(qb[tf].w*QS);
    aq[tf] = u.v;
  }

  // commit tile 0 image, then issue tile 1 loads (1-deep pipeline)
  stageWrite(0);
  if (NT > 1) {
    stageLoad(kt_hi - 1);
    __builtin_amdgcn_sched_barrier(0);
  }
  __syncthreads();

  f32x16 acc[2];
  #pragma unroll
  for (int db = 0; db < 2; ++db)
    #pragma unroll
    for (int r = 0; r < 16; ++r) acc[db][r] = 0.0f;
  float lsum = 0.0f;

  for (int i = 0; i < NT; ++i) {
    const int kt = kt_hi - i;
    const int k0 = kt * KT;

    // ---- per-wave skip of fully-masked tiles (wave-uniform branch) ----
    const bool active = (k0 <= hi) && (k0 + KT - 1 >= lo - (WIN - 1));
    if (active) {
      const char* kbuf = (const char*)&KsL[i & 1][0];
      const char* vbuf = (const char*)&VtL[i & 1][0];

      // ---- S^T = K Q^T : lane holds P[k = 32*kb + a(r) + 4h][q = lo+ql] ----
      f32x16 p[2];
      __builtin_amdgcn_s_setprio(1);
      #pragma unroll
      for (int kb = 0; kb < 2; ++kb) {
        const int krow = 32 * kb + ql;
        const int ksz = krow & 7;
        f32x16 c;
        #pragma unroll
        for (int r = 0; r < 16; ++r) c[r] = 0.0f;
        #pragma unroll
        for (int tf = 0; tf < 4; ++tf) {
          bf16x8 ka = *(const bf16x8*)(kbuf + krow * 128 + (((2*tf + h) ^ ksz) << 4));
          c = __builtin_amdgcn_mfma_f32_32x32x16_bf16(ka, aq[tf], c, 0, 0, 0);
        }
        p[kb] = c;
      }
      __builtin_amdgcn_s_setprio(0);

      // ---- exp2 (m=0 fixed shift, exact) + tree-reduced l-sum ----
      const int dbase = k0 - (lo + ql) + 4 * h;
      const bool needmask = (k0 + KT - 1 > lo) || (k0 < hi - (WIN - 1));
      float ps0 = 0.f, ps1 = 0.f, ps2 = 0.f, ps3 = 0.f;
      if (needmask) {
        #pragma unroll
        for (int kb = 0; kb < 2; ++kb)
          #pragma unroll
          for (int r = 0; r < 16; ++r) {
            const int dji = dbase + 32 * kb + ((r & 3) + 8 * (r >> 2));
            float s = ((unsigned)(dji + (WIN - 1)) <= (unsigned)(WIN - 1))
                          ? p[kb][r] : -1e30f;
            float e = __builtin_amdgcn_exp2f(s);
            p[kb][r] = e;
            if ((r & 3) == 0) ps0 += e;
            else if ((r & 3) == 1) ps1 += e;
            else if ((r & 3) == 2) ps2 += e;
            else ps3 += e;
          }
      } else {
        #pragma unroll
        for (int kb = 0; kb < 2; ++kb)
          #pragma unroll
          for (int r = 0; r < 16; ++r) {
            float e = __builtin_amdgcn_exp2f(p[kb][r]);
            p[kb][r] = e;
            if ((r & 3) == 0) ps0 += e;
            else if ((r & 3) == 1) ps1 += e;
            else if ((r & 3) == 2) ps2 += e;
            else ps3 += e;
          }
      }
      lsum += (ps0 + ps1) + (ps2 + ps3);

      // ---- in-register P transpose -> A-frags, fused with O += P V ----
      __builtin_amdgcn_s_setprio(1);
      #pragma unroll
      for (int kb = 0; kb < 2; ++kb) {
        #pragma unroll
        for (int b = 0; b < 2; ++b) {
          unsigned x0 = pkbf16(p[kb][8*b+0], p[kb][8*b+1]);
          unsigned x1 = pkbf16(p[kb][8*b+2], p[kb][8*b+3]);
          unsigned y0 = pkbf16(p[kb][8*b+4], p[kb][8*b+5]);
          unsigned y1 = pkbf16(p[kb][8*b+6], p[kb][8*b+7]);
          asm("v_permlane32_swap_b32 %0, %1" : "+v"(x0), "+v"(y0));
          asm("v_permlane32_swap_b32 %0, %1" : "+v"(x1), "+v"(y1));
          union { unsigned u[4]; bf16x8 v; } fa;
          fa.u[0] = x0; fa.u[1] = x1; fa.u[2] = y0; fa.u[3] = y1;
          const int ks = 2 * kb + b;   // k-slice 16*ks .. 16*ks+15
          #pragma unroll
          for (int db = 0; db < 2; ++db) {
            const int vrow = 32 * db + ql;
            bf16x8 vb = *(const bf16x8*)(vbuf + vrow * 128 +
                                         (((2*ks + h) ^ (vrow & 7)) << 4));
            acc[db] = __builtin_amdgcn_mfma_f32_32x32x16_bf16(fa.v, vb, acc[db], 0, 0, 0);
          }
        }
      }
      __builtin_amdgcn_s_setprio(0);
    }

    // ---- commit tile i+1's image; issue tile i+2's loads; one barrier ----
    if (i + 1 < NT) {
      stageWrite((i + 1) & 1);        // waits staged-reg vmcnt automatically
      if (i + 2 < NT) {
        stageLoad(kt - 2);            // regs free after cvt consumed them
        __builtin_amdgcn_sched_barrier(0);   // pin issue point (R8 fix)
      }
      __syncthreads();
    }
  }

  // ---- epilogue: cross-half l-sum, redistribute rcp to C rows, store ----
  float tot = lsum + __shfl_xor(lsum, 32, 64);
  float rcp = 1.0f / tot;              // valid for query lo+ql
  float rr[16];
  #pragma unroll
  for (int r = 0; r < 16; ++r)
    rr[r] = __shfl(rcp, ((r & 3) + 8 * (r >> 2)) + 4 * h, 64);
  #pragma unroll
  for (int db = 0; db < 2; ++db)
    #pragma unroll
    for (int r = 0; r < 16; ++r) {
      const int row = lo + ((r & 3) + 8 * (r >> 2)) + 4 * h;
      Og[base + (size_t)row * DH + 32 * db + ql] = acc[db][r] * rr[r];
    }
}

extern "C" void kernel_launch(void* const* d_in, const int* in_sizes, int n_in,
                              void* d_out, int out_size, void* d_ws, size_t ws_size,
                              hipStream_t stream) {
  const float* Q = (const float*)d_in[0];
  const float* K = (const float*)d_in[1];
  const float* V = (const float*)d_in[2];
  float* O = (float*)d_out;
  (void)d_ws; (void)ws_size;

  swa_attn_fused<<<dim3(SEQ / QT, NBATCH * NHEAD), dim3(512), 0, stream>>>(Q, K, V, O);
}

// Round 7
// 104.350 us; speedup vs baseline: 1.1831x; 1.0048x over previous
//
#include <hip/hip_runtime.h>

// Sliding-window causal attention, B=2 H=8 S=4096 D=64, window=512.
// R12: R11 + counted-barrier fix (T4). __syncthreads() emits
//   "s_waitcnt vmcnt(0) lgkmcnt(0); s_barrier", which forced the 10 global
//   loads issued by stageLoad(i+2) right before the barrier to COMPLETE
//   every phase (exposed HBM latency x 12 phases). Replaced with
//   "s_waitcnt lgkmcnt(0); s_barrier": LDS writes/reads drained (race-free
//   buffer swap), staged global loads stay in flight across the barrier and
//   are waited on only by the compiler's counted vmcnt before stageWrite
//   reads the staged registers one full compute phase later.

#define NBATCH 2
#define NHEAD  8
#define SEQ    4096
#define DH     64
#define WIN    512
#define QT     256
#define KT     64

typedef __attribute__((ext_vector_type(4)))  float f32x4;
typedef __attribute__((ext_vector_type(16))) float f32x16;
typedef __attribute__((ext_vector_type(8)))  short bf16x8;
typedef unsigned short ushort_t;

__device__ __forceinline__ unsigned short f2bf(float f) {
  unsigned u = __builtin_bit_cast(unsigned, f);
  u += 0x7fffu + ((u >> 16) & 1u);
  return (unsigned short)(u >> 16);
}

__device__ __forceinline__ unsigned pkbf16(float a, float b) {
  unsigned d;
  asm("v_cvt_pk_bf16_f32 %0, %1, %2" : "=v"(d) : "v"(a), "v"(b));
  return d;
}

// LDS-visibility barrier that does NOT drain vmcnt: in-flight global loads
// (register-staged prefetch) survive the barrier.
#define LDS_BARRIER() \
  __asm__ __volatile__("s_waitcnt lgkmcnt(0)\n\ts_barrier" ::: "memory")

// ---------------------------------------------------------------------------
// Fused attention: one block = 256 queries of one (b,h); 8 waves x 32 queries.
// LDS images (per tile, 8 KB each):
//   K: row = key (128 B), d-block blk=d/8 at byte ((blk ^ (key&7))<<4)
//   V: row = d  (128 B), key-block blk=key/8 at byte ((blk ^ (d&7))<<4)
// ---------------------------------------------------------------------------
__global__ __launch_bounds__(512, 1) void swa_attn_fused(
    const float* __restrict__ Qg, const float* __restrict__ Kg,
    const float* __restrict__ Vg, float* __restrict__ Og)
{
  // bijective XCD swizzle: 256 blocks, 8 XCDs, 32 blocks/XCD = 2 bh panels.
  const int flat = blockIdx.y * gridDim.x + blockIdx.x;      // 0..255
  const int swz  = (flat & 7) * 32 + (flat >> 3);
  const int qt = swz & 15, bh = swz >> 4;

  const int q0 = qt * QT;
  const size_t base = (size_t)bh * SEQ * DH;
  const int t = threadIdx.x, w = t >> 6, l = t & 63;
  const int ql = l & 31, h = l >> 5;

  __shared__ ushort_t KsL[2][4096];   // 16 KB double buffer
  __shared__ ushort_t VtL[2][4096];   // 16 KB double buffer  (32 KB total)

  const int kt_hi = 4 * qt + 3;
  const int kt_lo_raw = (q0 - (WIN - 1)) >> 6;               // floor div ok (q0>=0)
  const int kt_lo = kt_lo_raw > 0 ? kt_lo_raw : 0;
  const int NT = kt_hi - kt_lo + 1;   // 4..12

  const int lo = q0 + 32 * w;   // this wave's min query row
  const int hi = lo + 31;       // max query row

  // ---- staging state (held in registers across one compute phase) ----
  float4 kst[2];   // K: thread -> key = t>>3, d = 8*(t&7) .. +7
  float  vst[8];   // V: thread -> d-column t&63, keys 8*(t>>6) .. +7

  auto stageLoad = [&](int kt) {
    const int key = t >> 3, dseg = t & 7;
    const float* kp = Kg + base + (size_t)(kt * KT + key) * DH + dseg * 8;
    kst[0] = *(const float4*)(kp);
    kst[1] = *(const float4*)(kp + 4);
    const int vd = t & 63, vk0 = (t >> 6) * 8;
    const float* vp = Vg + base + (size_t)(kt * KT + vk0) * DH + vd;
    #pragma unroll
    for (int j = 0; j < 8; ++j) vst[j] = vp[j * DH];
  };
  auto stageWrite = [&](int buf) {
    const int key = t >> 3, dseg = t & 7;
    union { unsigned u[4]; uint4 q; } ok;
    ok.u[0] = pkbf16(kst[0].x, kst[0].y); ok.u[1] = pkbf16(kst[0].z, kst[0].w);
    ok.u[2] = pkbf16(kst[1].x, kst[1].y); ok.u[3] = pkbf16(kst[1].z, kst[1].w);
    *(uint4*)((char*)&KsL[buf][0] + key * 128 + ((dseg ^ (key & 7)) << 4)) = ok.q;
    const int vd = t & 63, vblk = t >> 6;
    union { unsigned u[4]; uint4 q; } ov;
    ov.u[0] = pkbf16(vst[0], vst[1]); ov.u[1] = pkbf16(vst[2], vst[3]);
    ov.u[2] = pkbf16(vst[4], vst[5]); ov.u[3] = pkbf16(vst[6], vst[7]);
    *(uint4*)((char*)&VtL[buf][0] + vd * 128 + ((vblk ^ (vd & 7)) << 4)) = ov.q;
  };

  // ---- Q loads FIRST, tile-0 staging loads immediately after ----
  const float* qrow = Qg + base + (size_t)(lo + ql) * DH;
  float4 qa[4], qb[4];
  #pragma unroll
  for (int tf = 0; tf < 4; ++tf) {
    qa[tf] = *(const float4*)(qrow + 16 * tf + 8 * h);
    qb[tf] = *(const float4*)(qrow + 16 * tf + 8 * h + 4);
  }
  stageLoad(kt_hi);
  __builtin_amdgcn_sched_barrier(0);

  // Q as B-frags, prescaled by (1/8)*log2(e) so softmax is raw v_exp_f32.
  const float QS = 0.125f * 1.44269504088896f;
  bf16x8 aq[4];
  #pragma unroll
  for (int tf = 0; tf < 4; ++tf) {
    union { unsigned short us[8]; bf16x8 v; } u;
    u.us[0]=f2bf(qa[tf].x*QS); u.us[1]=f2bf(qa[tf].y*QS);
    u.us[2]=f2bf(qa[tf].z*QS); u.us[3]=f2bf(qa[tf].w*QS);
    u.us[4]=f2bf(qb[tf].x*QS); u.us[5]=f2bf(qb[tf].y*QS);
    u.us[6]=f2bf(qb[tf].z*QS); u.us[7]=f2bf(qb[tf].w*QS);
    aq[tf] = u.v;
  }

  // commit tile 0 image, then issue tile 1 loads (1-deep pipeline)
  stageWrite(0);
  if (NT > 1) {
    stageLoad(kt_hi - 1);
    __builtin_amdgcn_sched_barrier(0);
  }
  LDS_BARRIER();   // LDS visibility only; tile-1 globals stay in flight

  f32x16 acc[2];
  #pragma unroll
  for (int db = 0; db < 2; ++db)
    #pragma unroll
    for (int r = 0; r < 16; ++r) acc[db][r] = 0.0f;
  float lsum = 0.0f;

  for (int i = 0; i < NT; ++i) {
    const int kt = kt_hi - i;
    const int k0 = kt * KT;

    // ---- per-wave skip of fully-masked tiles (wave-uniform branch) ----
    const bool active = (k0 <= hi) && (k0 + KT - 1 >= lo - (WIN - 1));
    if (active) {
      const char* kbuf = (const char*)&KsL[i & 1][0];
      const char* vbuf = (const char*)&VtL[i & 1][0];

      // ---- S^T = K Q^T : lane holds P[k = 32*kb + a(r) + 4h][q = lo+ql] ----
      f32x16 p[2];
      __builtin_amdgcn_s_setprio(1);
      #pragma unroll
      for (int kb = 0; kb < 2; ++kb) {
        const int krow = 32 * kb + ql;
        const int ksz = krow & 7;
        f32x16 c;
        #pragma unroll
        for (int r = 0; r < 16; ++r) c[r] = 0.0f;
        #pragma unroll
        for (int tf = 0; tf < 4; ++tf) {
          bf16x8 ka = *(const bf16x8*)(kbuf + krow * 128 + (((2*tf + h) ^ ksz) << 4));
          c = __builtin_amdgcn_mfma_f32_32x32x16_bf16(ka, aq[tf], c, 0, 0, 0);
        }
        p[kb] = c;
      }
      __builtin_amdgcn_s_setprio(0);

      // ---- exp2 (m=0 fixed shift, exact) + tree-reduced l-sum ----
      const int dbase = k0 - (lo + ql) + 4 * h;
      const bool needmask = (k0 + KT - 1 > lo) || (k0 < hi - (WIN - 1));
      float ps0 = 0.f, ps1 = 0.f, ps2 = 0.f, ps3 = 0.f;
      if (needmask) {
        #pragma unroll
        for (int kb = 0; kb < 2; ++kb)
          #pragma unroll
          for (int r = 0; r < 16; ++r) {
            const int dji = dbase + 32 * kb + ((r & 3) + 8 * (r >> 2));
            float s = ((unsigned)(dji + (WIN - 1)) <= (unsigned)(WIN - 1))
                          ? p[kb][r] : -1e30f;
            float e = __builtin_amdgcn_exp2f(s);
            p[kb][r] = e;
            if ((r & 3) == 0) ps0 += e;
            else if ((r & 3) == 1) ps1 += e;
            else if ((r & 3) == 2) ps2 += e;
            else ps3 += e;
          }
      } else {
        #pragma unroll
        for (int kb = 0; kb < 2; ++kb)
          #pragma unroll
          for (int r = 0; r < 16; ++r) {
            float e = __builtin_amdgcn_exp2f(p[kb][r]);
            p[kb][r] = e;
            if ((r & 3) == 0) ps0 += e;
            else if ((r & 3) == 1) ps1 += e;
            else if ((r & 3) == 2) ps2 += e;
            else ps3 += e;
          }
      }
      lsum += (ps0 + ps1) + (ps2 + ps3);

      // ---- in-register P transpose -> A-frags, fused with O += P V ----
      __builtin_amdgcn_s_setprio(1);
      #pragma unroll
      for (int kb = 0; kb < 2; ++kb) {
        #pragma unroll
        for (int b = 0; b < 2; ++b) {
          unsigned x0 = pkbf16(p[kb][8*b+0], p[kb][8*b+1]);
          unsigned x1 = pkbf16(p[kb][8*b+2], p[kb][8*b+3]);
          unsigned y0 = pkbf16(p[kb][8*b+4], p[kb][8*b+5]);
          unsigned y1 = pkbf16(p[kb][8*b+6], p[kb][8*b+7]);
          asm("v_permlane32_swap_b32 %0, %1" : "+v"(x0), "+v"(y0));
          asm("v_permlane32_swap_b32 %0, %1" : "+v"(x1), "+v"(y1));
          union { unsigned u[4]; bf16x8 v; } fa;
          fa.u[0] = x0; fa.u[1] = x1; fa.u[2] = y0; fa.u[3] = y1;
          const int ks = 2 * kb + b;   // k-slice 16*ks .. 16*ks+15
          #pragma unroll
          for (int db = 0; db < 2; ++db) {
            const int vrow = 32 * db + ql;
            bf16x8 vb = *(const bf16x8*)(vbuf + vrow * 128 +
                                         (((2*ks + h) ^ (vrow & 7)) << 4));
            acc[db] = __builtin_amdgcn_mfma_f32_32x32x16_bf16(fa.v, vb, acc[db], 0, 0, 0);
          }
        }
      }
      __builtin_amdgcn_s_setprio(0);
    }

    // ---- commit tile i+1's image; issue tile i+2's loads; LDS barrier ----
    if (i + 1 < NT) {
      stageWrite((i + 1) & 1);        // counted vmcnt wait on tile i+1 loads
      if (i + 2 < NT) {
        stageLoad(kt - 2);            // regs free after cvt consumed them
        __builtin_amdgcn_sched_barrier(0);   // pin issue point (R8 fix)
      }
      LDS_BARRIER();                  // tile i+2 globals stay in flight
    }
  }

  // ---- epilogue: cross-half l-sum, redistribute rcp to C rows, store ----
  float tot = lsum + __shfl_xor(lsum, 32, 64);
  float rcp = 1.0f / tot;              // valid for query lo+ql
  float rr[16];
  #pragma unroll
  for (int r = 0; r < 16; ++r)
    rr[r] = __shfl(rcp, ((r & 3) + 8 * (r >> 2)) + 4 * h, 64);
  #pragma unroll
  for (int db = 0; db < 2; ++db)
    #pragma unroll
    for (int r = 0; r < 16; ++r) {
      const int row = lo + ((r & 3) + 8 * (r >> 2)) + 4 * h;
      Og[base + (size_t)row * DH + 32 * db + ql] = acc[db][r] * rr[r];
    }
}

extern "C" void kernel_launch(void* const* d_in, const int* in_sizes, int n_in,
                              void* d_out, int out_size, void* d_ws, size_t ws_size,
                              hipStream_t stream) {
  const float* Q = (const float*)d_in[0];
  const float* K = (const float*)d_in[1];
  const float* V = (const float*)d_in[2];
  float* O = (float*)d_out;
  (void)d_ws; (void)ws_size;

  swa_attn_fused<<<dim3(SEQ / QT, NBATCH * NHEAD), dim3(512), 0, stream>>>(Q, K, V, O);
}

// Round 8
// 103.499 us; speedup vs baseline: 1.1928x; 1.0082x over previous
//
#include <hip/hip_runtime.h>

// Sliding-window causal attention, B=2 H=8 S=4096 D=64, window=512.
// R13: R12 + 2-tiles-per-phase (barrier count halved, 12 -> 6).
//   4-slot LDS ring (64 KB) for K and V images; two staging register sets
//   (A/B); per phase: compute tile 2j then 2j+1, commit next two images,
//   issue the following two tiles' loads, one lgkm-only barrier.
//   NT is always even (4/8/12) so phases pair exactly, no tail.
//   Inner tile geometry (swizzles, fragments, mask, m=0 exp2 softmax,
//   in-register P transpose, setprio, XCD swizzle) identical to R12.

#define NBATCH 2
#define NHEAD  8
#define SEQ    4096
#define DH     64
#define WIN    512
#define QT     256
#define KT     64

typedef __attribute__((ext_vector_type(4)))  float f32x4;
typedef __attribute__((ext_vector_type(16))) float f32x16;
typedef __attribute__((ext_vector_type(8)))  short bf16x8;
typedef unsigned short ushort_t;

__device__ __forceinline__ unsigned short f2bf(float f) {
  unsigned u = __builtin_bit_cast(unsigned, f);
  u += 0x7fffu + ((u >> 16) & 1u);
  return (unsigned short)(u >> 16);
}

__device__ __forceinline__ unsigned pkbf16(float a, float b) {
  unsigned d;
  asm("v_cvt_pk_bf16_f32 %0, %1, %2" : "=v"(d) : "v"(a), "v"(b));
  return d;
}

// LDS-visibility barrier that does NOT drain vmcnt: in-flight global loads
// (register-staged prefetch) survive the barrier.
#define LDS_BARRIER() \
  __asm__ __volatile__("s_waitcnt lgkmcnt(0)\n\ts_barrier" ::: "memory")

// ---------------------------------------------------------------------------
// Fused attention: one block = 256 queries of one (b,h); 8 waves x 32 queries.
// LDS images (per tile, 8 KB each):
//   K: row = key (128 B), d-block blk=d/8 at byte ((blk ^ (key&7))<<4)
//   V: row = d  (128 B), key-block blk=key/8 at byte ((blk ^ (d&7))<<4)
// ---------------------------------------------------------------------------
__global__ __launch_bounds__(512, 1) void swa_attn_fused(
    const float* __restrict__ Qg, const float* __restrict__ Kg,
    const float* __restrict__ Vg, float* __restrict__ Og)
{
  // bijective XCD swizzle: 256 blocks, 8 XCDs, 32 blocks/XCD = 2 bh panels.
  const int flat = blockIdx.y * gridDim.x + blockIdx.x;      // 0..255
  const int swz  = (flat & 7) * 32 + (flat >> 3);
  const int qt = swz & 15, bh = swz >> 4;

  const int q0 = qt * QT;
  const size_t base = (size_t)bh * SEQ * DH;
  const int t = threadIdx.x, w = t >> 6, l = t & 63;
  const int ql = l & 31, h = l >> 5;

  __shared__ ushort_t KsL[4][4096];   // 32 KB, 4-slot ring
  __shared__ ushort_t VtL[4][4096];   // 32 KB, 4-slot ring (64 KB total)

  const int kt_hi = 4 * qt + 3;
  const int kt_lo_raw = (q0 - (WIN - 1)) >> 6;
  const int kt_lo = kt_lo_raw > 0 ? kt_lo_raw : 0;
  const int NT = kt_hi - kt_lo + 1;   // 4, 8 or 12 — always even
  const int NPH = NT >> 1;            // 2, 4 or 6 two-tile phases

  const int lo = q0 + 32 * w;   // this wave's min query row
  const int hi = lo + 31;       // max query row

  // ---- staging: two independent register sets (A = even tile, B = odd) ----
  const int key = t >> 3, dseg = t & 7;      // K staging coords
  const int vd = t & 63,  vblk = t >> 6;     // V staging coords
  float4 kstA[2], kstB[2];
  float  vstA[8], vstB[8];

  auto loadA = [&](int kt) {
    const float* kp = Kg + base + (size_t)(kt * KT + key) * DH + dseg * 8;
    kstA[0] = *(const float4*)(kp);
    kstA[1] = *(const float4*)(kp + 4);
    const float* vp = Vg + base + (size_t)(kt * KT + vblk * 8) * DH + vd;
    #pragma unroll
    for (int j = 0; j < 8; ++j) vstA[j] = vp[j * DH];
  };
  auto loadB = [&](int kt) {
    const float* kp = Kg + base + (size_t)(kt * KT + key) * DH + dseg * 8;
    kstB[0] = *(const float4*)(kp);
    kstB[1] = *(const float4*)(kp + 4);
    const float* vp = Vg + base + (size_t)(kt * KT + vblk * 8) * DH + vd;
    #pragma unroll
    for (int j = 0; j < 8; ++j) vstB[j] = vp[j * DH];
  };
  auto writeA = [&](int buf) {
    union { unsigned u[4]; uint4 q; } ok;
    ok.u[0] = pkbf16(kstA[0].x, kstA[0].y); ok.u[1] = pkbf16(kstA[0].z, kstA[0].w);
    ok.u[2] = pkbf16(kstA[1].x, kstA[1].y); ok.u[3] = pkbf16(kstA[1].z, kstA[1].w);
    *(uint4*)((char*)&KsL[buf][0] + key * 128 + ((dseg ^ (key & 7)) << 4)) = ok.q;
    union { unsigned u[4]; uint4 q; } ov;
    ov.u[0] = pkbf16(vstA[0], vstA[1]); ov.u[1] = pkbf16(vstA[2], vstA[3]);
    ov.u[2] = pkbf16(vstA[4], vstA[5]); ov.u[3] = pkbf16(vstA[6], vstA[7]);
    *(uint4*)((char*)&VtL[buf][0] + vd * 128 + ((vblk ^ (vd & 7)) << 4)) = ov.q;
  };
  auto writeB = [&](int buf) {
    union { unsigned u[4]; uint4 q; } ok;
    ok.u[0] = pkbf16(kstB[0].x, kstB[0].y); ok.u[1] = pkbf16(kstB[0].z, kstB[0].w);
    ok.u[2] = pkbf16(kstB[1].x, kstB[1].y); ok.u[3] = pkbf16(kstB[1].z, kstB[1].w);
    *(uint4*)((char*)&KsL[buf][0] + key * 128 + ((dseg ^ (key & 7)) << 4)) = ok.q;
    union { unsigned u[4]; uint4 q; } ov;
    ov.u[0] = pkbf16(vstB[0], vstB[1]); ov.u[1] = pkbf16(vstB[2], vstB[3]);
    ov.u[2] = pkbf16(vstB[4], vstB[5]); ov.u[3] = pkbf16(vstB[6], vstB[7]);
    *(uint4*)((char*)&VtL[buf][0] + vd * 128 + ((vblk ^ (vd & 7)) << 4)) = ov.q;
  };

  // ---- Q loads FIRST, tiles 0/1 staging loads immediately after ----
  const float* qrow = Qg + base + (size_t)(lo + ql) * DH;
  float4 qa[4], qb[4];
  #pragma unroll
  for (int tf = 0; tf < 4; ++tf) {
    qa[tf] = *(const float4*)(qrow + 16 * tf + 8 * h);
    qb[tf] = *(const float4*)(qrow + 16 * tf + 8 * h + 4);
  }
  loadA(kt_hi);
  loadB(kt_hi - 1);
  __builtin_amdgcn_sched_barrier(0);

  // Q as B-frags, prescaled by (1/8)*log2(e) so softmax is raw v_exp_f32.
  const float QS = 0.125f * 1.44269504088896f;
  bf16x8 aq[4];
  #pragma unroll
  for (int tf = 0; tf < 4; ++tf) {
    union { unsigned short us[8]; bf16x8 v; } u;
    u.us[0]=f2bf(qa[tf].x*QS); u.us[1]=f2bf(qa[tf].y*QS);
    u.us[2]=f2bf(qa[tf].z*QS); u.us[3]=f2bf(qa[tf].w*QS);
    u.us[4]=f2bf(qb[tf].x*QS); u.us[5]=f2bf(qb[tf].y*QS);
    u.us[6]=f2bf(qb[tf].z*QS); u.us[7]=f2bf(qb[tf].w*QS);
    aq[tf] = u.v;
  }

  // commit tiles 0/1, then issue tiles 2/3 loads (consumed at end of phase 0)
  writeA(0);
  writeB(1);
  if (NPH > 1) {
    loadA(kt_hi - 2);
    loadB(kt_hi - 3);
    __builtin_amdgcn_sched_barrier(0);
  }
  LDS_BARRIER();   // LDS visibility only; staged globals stay in flight

  f32x16 acc[2];
  #pragma unroll
  for (int db = 0; db < 2; ++db)
    #pragma unroll
    for (int r = 0; r < 16; ++r) acc[db][r] = 0.0f;
  float lsum = 0.0f;

  auto computeTile = [&](const char* kbuf, const char* vbuf, int k0) {
    // ---- per-wave skip of fully-masked tiles (wave-uniform branch) ----
    const bool active = (k0 <= hi) && (k0 + KT - 1 >= lo - (WIN - 1));
    if (!active) return;

    // ---- S^T = K Q^T : lane holds P[k = 32*kb + a(r) + 4h][q = lo+ql] ----
    f32x16 p[2];
    __builtin_amdgcn_s_setprio(1);
    #pragma unroll
    for (int kb = 0; kb < 2; ++kb) {
      const int krow = 32 * kb + ql;
      const int ksz = krow & 7;
      f32x16 c;
      #pragma unroll
      for (int r = 0; r < 16; ++r) c[r] = 0.0f;
      #pragma unroll
      for (int tf = 0; tf < 4; ++tf) {
        bf16x8 ka = *(const bf16x8*)(kbuf + krow * 128 + (((2*tf + h) ^ ksz) << 4));
        c = __builtin_amdgcn_mfma_f32_32x32x16_bf16(ka, aq[tf], c, 0, 0, 0);
      }
      p[kb] = c;
    }
    __builtin_amdgcn_s_setprio(0);

    // ---- exp2 (m=0 fixed shift, exact) + tree-reduced l-sum ----
    const int dbase = k0 - (lo + ql) + 4 * h;
    const bool needmask = (k0 + KT - 1 > lo) || (k0 < hi - (WIN - 1));
    float ps0 = 0.f, ps1 = 0.f, ps2 = 0.f, ps3 = 0.f;
    if (needmask) {
      #pragma unroll
      for (int kb = 0; kb < 2; ++kb)
        #pragma unroll
        for (int r = 0; r < 16; ++r) {
          const int dji = dbase + 32 * kb + ((r & 3) + 8 * (r >> 2));
          float s = ((unsigned)(dji + (WIN - 1)) <= (unsigned)(WIN - 1))
                        ? p[kb][r] : -1e30f;
          float e = __builtin_amdgcn_exp2f(s);
          p[kb][r] = e;
          if ((r & 3) == 0) ps0 += e;
          else if ((r & 3) == 1) ps1 += e;
          else if ((r & 3) == 2) ps2 += e;
          else ps3 += e;
        }
    } else {
      #pragma unroll
      for (int kb = 0; kb < 2; ++kb)
        #pragma unroll
        for (int r = 0; r < 16; ++r) {
          float e = __builtin_amdgcn_exp2f(p[kb][r]);
          p[kb][r] = e;
          if ((r & 3) == 0) ps0 += e;
          else if ((r & 3) == 1) ps1 += e;
          else if ((r & 3) == 2) ps2 += e;
          else ps3 += e;
        }
    }
    lsum += (ps0 + ps1) + (ps2 + ps3);

    // ---- in-register P transpose -> A-frags, fused with O += P V ----
    __builtin_amdgcn_s_setprio(1);
    #pragma unroll
    for (int kb = 0; kb < 2; ++kb) {
      #pragma unroll
      for (int b = 0; b < 2; ++b) {
        unsigned x0 = pkbf16(p[kb][8*b+0], p[kb][8*b+1]);
        unsigned x1 = pkbf16(p[kb][8*b+2], p[kb][8*b+3]);
        unsigned y0 = pkbf16(p[kb][8*b+4], p[kb][8*b+5]);
        unsigned y1 = pkbf16(p[kb][8*b+6], p[kb][8*b+7]);
        asm("v_permlane32_swap_b32 %0, %1" : "+v"(x0), "+v"(y0));
        asm("v_permlane32_swap_b32 %0, %1" : "+v"(x1), "+v"(y1));
        union { unsigned u[4]; bf16x8 v; } fa;
        fa.u[0] = x0; fa.u[1] = x1; fa.u[2] = y0; fa.u[3] = y1;
        const int ks = 2 * kb + b;   // k-slice 16*ks .. 16*ks+15
        #pragma unroll
        for (int db = 0; db < 2; ++db) {
          const int vrow = 32 * db + ql;
          bf16x8 vb = *(const bf16x8*)(vbuf + vrow * 128 +
                                       (((2*ks + h) ^ (vrow & 7)) << 4));
          acc[db] = __builtin_amdgcn_mfma_f32_32x32x16_bf16(fa.v, vb, acc[db], 0, 0, 0);
        }
      }
    }
    __builtin_amdgcn_s_setprio(0);
  };

  for (int j = 0; j < NPH; ++j) {
    const int ktA = kt_hi - 2 * j;
    const int sA = (2 * j) & 3, sB = (2 * j + 1) & 3;

    computeTile((const char*)&KsL[sA][0], (const char*)&VtL[sA][0], ktA * KT);
    computeTile((const char*)&KsL[sB][0], (const char*)&VtL[sB][0], (ktA - 1) * KT);

    if (j + 1 < NPH) {
      // commit tiles ktA-2 / ktA-3 (loads issued one full phase ago)
      writeA((2 * j + 2) & 3);
      writeB((2 * j + 3) & 3);
      if (j + 2 < NPH) {
        loadA(ktA - 4);               // feeds writes at end of phase j+1
        loadB(ktA - 5);
        __builtin_amdgcn_sched_barrier(0);   // pin issue point
      }
      LDS_BARRIER();                  // staged globals stay in flight
    }
  }

  // ---- epilogue: cross-half l-sum, redistribute rcp to C rows, store ----
  float tot = lsum + __shfl_xor(lsum, 32, 64);
  float rcp = 1.0f / tot;              // valid for query lo+ql
  float rr[16];
  #pragma unroll
  for (int r = 0; r < 16; ++r)
    rr[r] = __shfl(rcp, ((r & 3) + 8 * (r >> 2)) + 4 * h, 64);
  #pragma unroll
  for (int db = 0; db < 2; ++db)
    #pragma unroll
    for (int r = 0; r < 16; ++r) {
      const int row = lo + ((r & 3) + 8 * (r >> 2)) + 4 * h;
      Og[base + (size_t)row * DH + 32 * db + ql] = acc[db][r] * rr[r];
    }
}

extern "C" void kernel_launch(void* const* d_in, const int* in_sizes, int n_in,
                              void* d_out, int out_size, void* d_ws, size_t ws_size,
                              hipStream_t stream) {
  const float* Q = (const float*)d_in[0];
  const float* K = (const float*)d_in[1];
  const float* V = (const float*)d_in[2];
  float* O = (float*)d_out;
  (void)d_ws; (void)ws_size;

  swa_attn_fused<<<dim3(SEQ / QT, NBATCH * NHEAD), dim3(512), 0, stream>>>(Q, K, V, O);
}